// Round 14
// baseline (203.656 us; speedup 1.0000x reference)
//
#include <hip/hip_runtime.h>
#include <math.h>

#define B_ 2
#define S_ 4096
#define D_ 1024
#define M_ 4
#define N_ (B_*S_)   // 8192 rows
#define EPS 1e-6f

typedef unsigned short u16;
typedef __bf16 bf16x8 __attribute__((ext_vector_type(8)));
typedef float  f32x4  __attribute__((ext_vector_type(4)));

__device__ __forceinline__ float elu1(float x) {
    // F.elu(x)+1 : x>0 -> x+1 ; x<=0 -> exp(x)
    return x > 0.0f ? x + 1.0f : __expf(x);
}

// fp32 -> bf16 round-to-nearest-even (finite inputs)
__device__ __forceinline__ u16 f2b(float f) {
    unsigned int u = __float_as_uint(f);
    return (u16)((u + 0x7FFFu + ((u >> 16) & 1u)) >> 16);
}

// async global->LDS, 16B per lane; LDS dest = wave-uniform base + lane*16
#define GLDS16(gp, lp) __builtin_amdgcn_global_load_lds( \
    (const __attribute__((address_space(1))) void*)(gp), \
    (__attribute__((address_space(3))) void*)(lp), 16, 0, 0)

// ---------------- per-row Q stats: qnorm[m,r] + sigma(Q) bf16.
// Blocks 0..31 also zero knorm (8192) / colsum (1024) — consumed only by the
// LATER prep_k kernel, so no ordering hazard.
__global__ __launch_bounds__(256) void k1_stats(
    const float* __restrict__ Q, const float* __restrict__ mnorm,
    float* __restrict__ qnorm,   // (M,N)
    u16* __restrict__ sQ,        // (N,D) bf16
    float* __restrict__ knorm, float* __restrict__ colsum)
{
    int r = blockIdx.x;
    int t = threadIdx.x;
    if (r < 32) {
        knorm[r * 256 + t] = 0.0f;
        if (r < 4) colsum[r * 256 + t] = 0.0f;
    }
    float4 q4 = *(const float4*)(Q + (size_t)r * D_ + t * 4);
    float sq0 = elu1(q4.x), sq1 = elu1(q4.y), sq2 = elu1(q4.z), sq3 = elu1(q4.w);

    uint2 sv;
    sv.x = (unsigned)f2b(sq0) | ((unsigned)f2b(sq1) << 16);
    sv.y = (unsigned)f2b(sq2) | ((unsigned)f2b(sq3) << 16);
    *(uint2*)(sQ + (size_t)r * D_ + t * 4) = sv;

    float vals[M_];
    #pragma unroll
    for (int m = 0; m < M_; ++m) {
        float4 w4 = *(const float4*)(mnorm + m * D_ + t * 4);
        vals[m] = sq0 * w4.x + sq1 * w4.y + sq2 * w4.z + sq3 * w4.w;
    }

    __shared__ float sbuf[M_][4];
    int wave = t >> 6, lane = t & 63;
    #pragma unroll
    for (int i = 0; i < M_; ++i) {
        float v = vals[i];
        #pragma unroll
        for (int off = 32; off > 0; off >>= 1) v += __shfl_down(v, off, 64);
        if (lane == 0) sbuf[i][wave] = v;
    }
    __syncthreads();
    if (t == 0) {
        #pragma unroll
        for (int m = 0; m < M_; ++m)
            qnorm[(size_t)m * N_ + r] = sbuf[m][0] + sbuf[m][1] + sbuf[m][2] + sbuf[m][3];
    }
}

// ---------------- sigma(K): bf16 row-major + bf16 transposed + colsum + knorm (one K pass)
__global__ __launch_bounds__(256) void prep_k(
    const float* __restrict__ K, const float* __restrict__ mnorm,
    u16* __restrict__ sk, u16* __restrict__ skT,
    float* __restrict__ colsum, float* __restrict__ knorm)
{
    __shared__ float tile[64][65];
    __shared__ float mn0[64];
    int r0 = blockIdx.x * 64;
    int d0 = blockIdx.y * 64;
    int t = threadIdx.x;
    int rr = t >> 4, c4 = (t & 15) * 4;
    if (t >= 128 && t < 192) mn0[t - 128] = mnorm[d0 + (t - 128)];
    #pragma unroll
    for (int i = 0; i < 4; ++i) {
        int rri = rr + i * 16;
        float4 k4 = *(const float4*)(K + (size_t)(r0 + rri) * D_ + d0 + c4);
        float e0 = elu1(k4.x), e1 = elu1(k4.y), e2 = elu1(k4.z), e3 = elu1(k4.w);
        uint2 v; v.x = (unsigned)f2b(e0) | ((unsigned)f2b(e1) << 16);
        v.y = (unsigned)f2b(e2) | ((unsigned)f2b(e3) << 16);
        *(uint2*)(sk + (size_t)(r0 + rri) * D_ + d0 + c4) = v;
        tile[rri][c4 + 0] = e0; tile[rri][c4 + 1] = e1;
        tile[rri][c4 + 2] = e2; tile[rri][c4 + 3] = e3;
    }
    __syncthreads();
    #pragma unroll
    for (int i = 0; i < 4; ++i) {
        int dd = rr + i * 16;
        float v0 = tile[c4 + 0][dd], v1 = tile[c4 + 1][dd];
        float v2 = tile[c4 + 2][dd], v3 = tile[c4 + 3][dd];
        uint2 v; v.x = (unsigned)f2b(v0) | ((unsigned)f2b(v1) << 16);
        v.y = (unsigned)f2b(v2) | ((unsigned)f2b(v3) << 16);
        *(uint2*)(skT + (size_t)(d0 + dd) * N_ + r0 + c4) = v;
    }
    if (t < 64) {               // wave 0: knorm partial dot with mnorm row 0
        float s = 0.0f;
        #pragma unroll
        for (int j = 0; j < 64; ++j) s += tile[t][j] * mn0[j];
        atomicAdd(&knorm[r0 + t], s);
    } else if (t < 128) {       // wave 1: column sums
        int c = t - 64;
        float s = 0.0f;
        #pragma unroll
        for (int j = 0; j < 64; ++j) s += tile[j][c];
        atomicAdd(&colsum[d0 + c], s);
    }
}

// ---------------- memories (4,1024,1024) -> MemT bf16 [e][m*1024+d].
// m==0 blocks also copy the raw fp32 Mem0 tile into out_mem.
__global__ __launch_bounds__(256) void prep_memT(
    const float* __restrict__ Mem, u16* __restrict__ MemT,
    float* __restrict__ out_mem)
{
    __shared__ float tile[64][65];
    int m = blockIdx.z;
    int e0 = blockIdx.x * 64, d0 = blockIdx.y * 64;
    int t = threadIdx.x, rr = t >> 4, c4 = (t & 15) * 4;
    #pragma unroll
    for (int i = 0; i < 4; ++i) {
        int dd = rr + i * 16;
        float4 v4 = *(const float4*)(Mem + ((size_t)m * D_ + d0 + dd) * D_ + e0 + c4);
        tile[dd][c4 + 0] = v4.x; tile[dd][c4 + 1] = v4.y;
        tile[dd][c4 + 2] = v4.z; tile[dd][c4 + 3] = v4.w;
        if (m == 0)
            *(float4*)(out_mem + (size_t)(d0 + dd) * D_ + e0 + c4) = v4;
    }
    __syncthreads();
    #pragma unroll
    for (int i = 0; i < 4; ++i) {
        int ee = rr + i * 16;
        float v0 = tile[c4 + 0][ee], v1 = tile[c4 + 1][ee];
        float v2 = tile[c4 + 2][ee], v3 = tile[c4 + 3][ee];
        uint2 v; v.x = (unsigned)f2b(v0) | ((unsigned)f2b(v1) << 16);
        v.y = (unsigned)f2b(v2) | ((unsigned)f2b(v3) << 16);
        *(uint2*)(MemT + (size_t)(e0 + ee) * (M_ * D_) + m * D_ + d0 + c4) = v;
    }
}

// ---------------- weights: |mnorm| reduce + relsum (from qnorm) + softmax over m
__global__ __launch_bounds__(512) void k2_weights(
    const float* __restrict__ mnorm, const float* __restrict__ qnorm,
    float* __restrict__ weights)
{
    __shared__ float sbuf[12][8];
    int t = threadIdx.x, wave = t >> 6, lane = t & 63;
    float vals[12];
    #pragma unroll
    for (int m = 0; m < M_; ++m) {
        float v = 0.0f;
        for (int d = t; d < D_; d += 512) v += fabsf(mnorm[m * D_ + d]);
        vals[m] = v;
    }
    #pragma unroll
    for (int mb = 0; mb < M_ * B_; ++mb) {
        int m = mb >> 1, b = mb & 1;
        const float4* p = (const float4*)(qnorm + (size_t)m * N_ + (size_t)b * S_);
        float v = 0.0f;
        for (int i = t; i < S_ / 4; i += 512) {
            float4 x = p[i];
            v += x.x + x.y + x.z + x.w;
        }
        vals[4 + mb] = v;
    }
    #pragma unroll
    for (int i = 0; i < 12; ++i) {
        float v = vals[i];
        #pragma unroll
        for (int off = 32; off > 0; off >>= 1) v += __shfl_down(v, off, 64);
        if (lane == 0) sbuf[i][wave] = v;
    }
    __syncthreads();
    if (t == 0) {
        bool empty[M_]; bool all_empty = true;
        float relsum[M_ * B_];
        #pragma unroll
        for (int m = 0; m < M_; ++m) {
            float sa = 0.0f;
            #pragma unroll
            for (int w = 0; w < 8; ++w) sa += sbuf[m][w];
            empty[m] = (sa < EPS);
            all_empty = all_empty && empty[m];
        }
        #pragma unroll
        for (int mb = 0; mb < M_ * B_; ++mb) {
            float sv = 0.0f;
            #pragma unroll
            for (int w = 0; w < 8; ++w) sv += sbuf[4 + mb][w];
            relsum[mb] = sv;
        }
        for (int b = 0; b < B_; ++b) {
            float rel[M_]; float mx = -3.0e38f;
            #pragma unroll
            for (int m = 0; m < M_; ++m) {
                rel[m] = empty[m] ? -1.0e30f : relsum[m * B_ + b] * (1.0f / (float)S_);
                mx = fmaxf(mx, rel[m]);
            }
            float se = 0.0f;
            #pragma unroll
            for (int m = 0; m < M_; ++m) { rel[m] = __expf(rel[m] - mx); se += rel[m]; }
            #pragma unroll
            for (int m = 0; m < M_; ++m) {
                float wv = rel[m] / se;
                if (empty[m] || all_empty) wv = 0.0f;
                weights[m * B_ + b] = wv;
            }
        }
    }
}

// ---------------- ratio planes for in-accumulator c-folding + new_memory_norm output
__global__ __launch_bounds__(256) void k2_cvec(
    const float* __restrict__ qnorm, const float* __restrict__ weights,
    const float* __restrict__ mnorm, const float* __restrict__ colsum,
    float* __restrict__ ratT, float* __restrict__ norm_out)
{
    int g = blockIdx.x * 256 + threadIdx.x;
    if (g < N_) {
        int b = g / S_;
        float cs[M_];
        #pragma unroll
        for (int m = 0; m < M_; ++m)
            cs[m] = fmaxf(weights[m * B_ + b] / fmaxf(qnorm[(size_t)m * N_ + g], EPS), 1e-20f);
        ratT[0 * (size_t)N_ + g] = cs[0] / cs[1];
        ratT[1 * (size_t)N_ + g] = cs[1] / cs[2];
        ratT[2 * (size_t)N_ + g] = cs[2] / cs[3];
        ratT[3 * (size_t)N_ + g] = cs[3];
    }
    if (g < D_) norm_out[g] = mnorm[g] + colsum[g] * (1.0f / (float)B_);
}

// ================= 128²/4-wave GEMM core, COUNTED-VMCNT depth-2 (R5-verified pattern) =================
// acc += A[rb..rb+128][ak0..] * B[cb..cb+128][bk0..]^T, k-contig bf16. BK=32.
// THREE LDS buffers/operand (3x8KB): tiles t,t+1,t+2 in flight. Per step:
// wait vmcnt(4) (own tile-t loads landed; t+1's stay flying) -> barrier ->
// stage(t+2) -> MFMA(t). Never vmcnt(0) in the loop — in the new L2-resident
// regime (R13: FETCH 81MB, HBM 8%), one iteration of cover ~= the whole L2
// latency, which the old per-step drain exposed (~450 cy/step stall measured).
// WAR: stage(t+2) hits buf[(t-1)%3]; every wave's t-1 ds_reads completed
// before it passed barrier(t) (reads consumed by MFMAs pre-barrier).
// Trailing vmcnt(0)+lgkm(0)+barrier makes back-to-back segments safe.
__device__ __forceinline__ void tile_mma(
    const u16* Asb, const u16* Bsb, int aoff, int boff, f32x4 (&acc)[4][4])
{
    bf16x8 af[4], bf[4];
    #pragma unroll
    for (int i = 0; i < 4; ++i) {
        af[i] = *(const bf16x8*)((const char*)Asb + aoff + i * 1024);
        bf[i] = *(const bf16x8*)((const char*)Bsb + boff + i * 1024);
    }
    #pragma unroll
    for (int mi = 0; mi < 4; ++mi)
        #pragma unroll
        for (int ni = 0; ni < 4; ++ni)
            acc[mi][ni] = __builtin_amdgcn_mfma_f32_16x16x32_bf16(
                af[mi], bf[ni], acc[mi][ni], 0, 0, 0);
}

__device__ __forceinline__ void gemm_seg(
    u16* As, u16* Bs,   // each [3][4096] u16 in LDS
    const u16* __restrict__ A, int lda, int ak0,
    const u16* __restrict__ B, int ldb, int bk0,
    int rb, int cb, int klen,
    f32x4 (&acc)[4][4])
{
    const int tid  = threadIdx.x;
    const int lane = tid & 63;
    const int wid  = tid >> 6;
    const int wr   = wid >> 1, wc = wid & 1;
    const int r15  = lane & 15;

    const int srow0 = (wid * 2 + 0) * 16 + (lane >> 2);
    const int srow1 = (wid * 2 + 1) * 16 + (lane >> 2);
    const int sg    = ((lane & 3) ^ ((lane >> 3) & 3)) * 8;
    const u16* Ag0 = A + (size_t)(rb + srow0) * lda + ak0 + sg;
    const u16* Ag1 = A + (size_t)(rb + srow1) * lda + ak0 + sg;
    const u16* Bg0 = B + (size_t)(cb + srow0) * ldb + bk0 + sg;
    const u16* Bg1 = B + (size_t)(cb + srow1) * ldb + bk0 + sg;
    const int lo0 = (wid * 2 + 0) * 512;
    const int lo1 = (wid * 2 + 1) * 512;

    const int xo   = (((lane >> 4) ^ ((r15 >> 1) & 3)) * 16);
    const int aoff = (wr * 64 + r15) * 64 + xo;
    const int boff = (wc * 64 + r15) * 64 + xo;

    const int nt = klen >> 5;   // >= 2 for all call sites (min klen = 1024)

    // prologue: stage tiles 0,1 into buffers 0,1 (8 loads outstanding)
    GLDS16(Ag0, As + lo0);
    GLDS16(Ag1, As + lo1);
    GLDS16(Bg0, Bs + lo0);
    GLDS16(Bg1, Bs + lo1);
    GLDS16(Ag0 + 32, As + 4096 + lo0);
    GLDS16(Ag1 + 32, As + 4096 + lo1);
    GLDS16(Bg0 + 32, Bs + 4096 + lo0);
    GLDS16(Bg1 + 32, Bs + 4096 + lo1);

    int bcur = 0;   // buffer of tile t (= t % 3)
    for (int t = 0; t < nt - 1; ++t) {
        asm volatile("s_waitcnt vmcnt(4)" ::: "memory");
        __builtin_amdgcn_s_barrier();
        if (t + 2 < nt) {
            int bn = bcur ? bcur - 1 : 2;        // (t+2) % 3
            int kt = (t + 2) << 5;
            GLDS16(Ag0 + kt, As + bn * 4096 + lo0);
            GLDS16(Ag1 + kt, As + bn * 4096 + lo1);
            GLDS16(Bg0 + kt, Bs + bn * 4096 + lo0);
            GLDS16(Bg1 + kt, Bs + bn * 4096 + lo1);
        }
        tile_mma(As + bcur * 4096, Bs + bcur * 4096, aoff, boff, acc);
        bcur = (bcur + 1 == 3) ? 0 : bcur + 1;
    }
    // epilogue: last tile
    asm volatile("s_waitcnt vmcnt(0)" ::: "memory");
    __builtin_amdgcn_s_barrier();
    tile_mma(As + bcur * 4096, Bs + bcur * 4096, aoff, boff, acc);
    // WAR fence for the NEXT segment's staging into these buffers
    asm volatile("s_waitcnt lgkmcnt(0)" ::: "memory");
    __builtin_amdgcn_s_barrier();
}

// ---------------- epilogues
__device__ __forceinline__ void epi_out(
    f32x4 (&acc)[4][4], float* __restrict__ out, int rb, int cb)
{
    int lane = threadIdx.x & 63, wid = threadIdx.x >> 6;
    int wr = wid >> 1, wc = wid & 1, r15 = lane & 15;
    #pragma unroll
    for (int mi = 0; mi < 4; ++mi) {
        int row0 = rb + wr * 64 + mi * 16 + (lane >> 4) * 4;
        #pragma unroll
        for (int ni = 0; ni < 4; ++ni) {
            int col = cb + wc * 64 + ni * 16 + r15;
            #pragma unroll
            for (int r = 0; r < 4; ++r)
                out[(size_t)(row0 + r) * D_ + col] = acc[mi][ni][r];
        }
    }
}

__device__ __forceinline__ void epi_delta(
    f32x4 (&acc)[4][4], const float* __restrict__ V,
    const float* __restrict__ knorm, u16* __restrict__ deltaT,
    int rb, int cb)
{
    int lane = threadIdx.x & 63, wid = threadIdx.x >> 6;
    int wr = wid >> 1, wc = wid & 1, r15 = lane & 15;
    #pragma unroll
    for (int mi = 0; mi < 4; ++mi) {
        int row0 = rb + wr * 64 + mi * 16 + (lane >> 4) * 4;
        float inv[4];
        #pragma unroll
        for (int r = 0; r < 4; ++r) inv[r] = 1.0f / fmaxf(knorm[row0 + r], EPS);
        #pragma unroll
        for (int ni = 0; ni < 4; ++ni) {
            int col = cb + wc * 64 + ni * 16 + r15;
            float dv[4];
            #pragma unroll
            for (int r = 0; r < 4; ++r)
                dv[r] = V[(size_t)(row0 + r) * D_ + col] - acc[mi][ni][r] * inv[r];
            uint2 pv;
            pv.x = (unsigned)f2b(dv[0]) | ((unsigned)f2b(dv[1]) << 16);
            pv.y = (unsigned)f2b(dv[2]) | ((unsigned)f2b(dv[3]) << 16);
            *(uint2*)(deltaT + (size_t)col * N_ + row0) = pv;  // lanes 0/16/32/48 coalesce
        }
    }
}

// ---------------- FUSED retrieve + delta, ROW-PANEL-per-XCD mapping (R13-proven:
// FETCH 350->81MB). XCD x owns output-row panel by in [8x,8x+8) x all bx.
// Retrieve: A = sigma(Q) in 4 K-segments; c_m folded into the accumulator
// between segments (acc *= ratT plane) -> no Ac materialization.
__global__ __launch_bounds__(256, 3) void g34_fused(
    const u16* __restrict__ sQ, const u16* __restrict__ MemT,
    const u16* __restrict__ sk, const float* __restrict__ V,
    const float* __restrict__ knorm, const float* __restrict__ ratT,
    float* __restrict__ out, u16* __restrict__ deltaT)
{
    __shared__ u16 As[3 * 4096];
    __shared__ u16 Bs[3 * 4096];
    int hw = blockIdx.x;
    int x   = hw & 7;            // XCD (HW round-robins blockIdx % 8)
    int l   = hw >> 3;           // [0,128) within XCD
    int z   = l >> 6;            // 0: retrieve (hw<512), 1: delta
    int idx = l & 63;
    int by  = x * 8 + (idx >> 3);  // XCD-owned row-panel range
    int bx  = idx & 7;
    int rb = by * 128, cb = bx * 128;
    int lane = threadIdx.x & 63, wid = threadIdx.x >> 6;
    int wr = wid >> 1;
    f32x4 acc[4][4];
    #pragma unroll
    for (int i = 0; i < 4; ++i)
        #pragma unroll
        for (int j = 0; j < 4; ++j) {
            f32x4 zz = {0.0f, 0.0f, 0.0f, 0.0f};
            acc[i][j] = zz;
        }
    if (z == 0) {
        #pragma unroll 1
        for (int m = 0; m < M_; ++m) {
            gemm_seg(As, Bs, sQ, D_, 0, MemT, M_ * D_, m * D_, rb, cb, D_, acc);
            const float* rp = ratT + (size_t)m * N_;
            #pragma unroll
            for (int mi = 0; mi < 4; ++mi) {
                int row0 = rb + wr * 64 + mi * 16 + (lane >> 4) * 4;
                float4 rt = *(const float4*)(rp + row0);
                #pragma unroll
                for (int ni = 0; ni < 4; ++ni) {
                    acc[mi][ni][0] *= rt.x; acc[mi][ni][1] *= rt.y;
                    acc[mi][ni][2] *= rt.z; acc[mi][ni][3] *= rt.w;
                }
            }
        }
        epi_out(acc, out, rb, cb);
    } else {
        gemm_seg(As, Bs, sk, D_, 0, MemT, M_ * D_, 0, rb, cb, D_, acc);
        epi_delta(acc, V, knorm, deltaT, rb, cb);
    }
}

// ---------------- update: out_mem(D,D) += (skT * deltaT^T)/N, split-K=8, fp32 atomics.
// K-SLICE-per-XCD mapping: kz = hw&7 == XCD -> each XCD reads only its
// skT/deltaT k-slice (2MB+2MB, L2-resident) instead of re-streaming 32MB.
#define KSPLIT 8
__global__ __launch_bounds__(256, 3) void g5_update(
    const u16* __restrict__ skT, const u16* __restrict__ deltaT,
    float* __restrict__ memout)
{
    __shared__ u16 As[3 * 4096];
    __shared__ u16 Bs[3 * 4096];
    f32x4 acc[4][4];
    #pragma unroll
    for (int i = 0; i < 4; ++i)
        #pragma unroll
        for (int j = 0; j < 4; ++j) {
            f32x4 zz = {0.0f, 0.0f, 0.0f, 0.0f};
            acc[i][j] = zz;
        }
    int hw = blockIdx.x;
    int kz = hw & 7;             // XCD owns one k-slice
    int l  = hw >> 3;            // [0,64)
    int by = l >> 3, bx = l & 7;
    int rb = by * 128, cb = bx * 128;
    int k0 = kz * (N_ / KSPLIT);
    gemm_seg(As, Bs, skT, N_, k0, deltaT, N_, k0, rb, cb, N_ / KSPLIT, acc);
    int lane = threadIdx.x & 63, wid = threadIdx.x >> 6;
    int wr = wid >> 1, wc = wid & 1, r15 = lane & 15;
    const float sc = 1.0f / (float)N_;
    #pragma unroll
    for (int mi = 0; mi < 4; ++mi) {
        int row0 = rb + wr * 64 + mi * 16 + (lane >> 4) * 4;
        #pragma unroll
        for (int ni = 0; ni < 4; ++ni) {
            int col = cb + wc * 64 + ni * 16 + r15;
            #pragma unroll
            for (int r = 0; r < 4; ++r)
                atomicAdd(memout + (size_t)(row0 + r) * D_ + col, acc[mi][ni][r] * sc);
        }
    }
}

extern "C" void kernel_launch(void* const* d_in, const int* in_sizes, int n_in,
                              void* d_out, int out_size, void* d_ws, size_t ws_size,
                              hipStream_t stream) {
    const float* Q     = (const float*)d_in[0];
    const float* K     = (const float*)d_in[1];
    const float* V     = (const float*)d_in[2];
    const float* Mem   = (const float*)d_in[3];
    const float* Mnorm = (const float*)d_in[4];

    float* out      = (float*)d_out;
    float* out_mem  = out + (size_t)N_ * D_;        // D*D
    float* out_norm = out_mem + (size_t)D_ * D_;    // D

    // ---- workspace layout (needs ~74MB; ws >= 121MB proven in prior rounds) ----
    // [0,1MB):   fp32 stats: qnorm(M*N) knorm(N) colsum(D) weights(8) ratT(4*N)
    // [1,9MB):   MemT  bf16 [1024][4096]
    // [9,25MB):  sk    bf16 [8192][1024]
    // [25,41MB): skT   bf16 [1024][8192]
    // [41,57MB): sQ    bf16 [8192][1024]
    // [57,73MB): deltaT bf16 [1024][8192]
    char* wsb = (char*)d_ws;
    float* qnorm   = (float*)wsb;                   // 32768
    float* knorm   = qnorm + (size_t)M_ * N_;       // 8192
    float* colsum  = knorm + N_;                    // 1024
    float* weights = colsum + D_;                   // 8
    float* ratT    = weights + M_ * B_;             // 4*N = 32768 (16B aligned)
    u16* MemT   = (u16*)(wsb + (size_t)1  * (1 << 20));
    u16* sk     = (u16*)(wsb + (size_t)9  * (1 << 20));
    u16* skT    = (u16*)(wsb + (size_t)25 * (1 << 20));
    u16* sQ     = (u16*)(wsb + (size_t)41 * (1 << 20));
    u16* deltaT = (u16*)(wsb + (size_t)57 * (1 << 20));

    hipLaunchKernelGGL(k1_stats, dim3(N_), dim3(256), 0, stream, Q, Mnorm, qnorm, sQ, knorm, colsum);
    hipLaunchKernelGGL(prep_k, dim3(128, 16), dim3(256), 0, stream, K, Mnorm, sk, skT, colsum, knorm);
    hipLaunchKernelGGL(prep_memT, dim3(16, 16, 4), dim3(256), 0, stream, Mem, MemT, out_mem);
    hipLaunchKernelGGL(k2_weights, dim3(1), dim3(512), 0, stream, Mnorm, qnorm, weights);
    hipLaunchKernelGGL(k2_cvec, dim3(32), dim3(256), 0, stream, qnorm, weights, Mnorm, colsum, ratT, out_norm);
    hipLaunchKernelGGL(g34_fused, dim3(1024), dim3(256), 0, stream,
                       sQ, MemT, sk, V, knorm, ratT, out, deltaT);
    hipLaunchKernelGGL(g5_update, dim3(512), dim3(256), 0, stream, skT, deltaT, out_mem);
}

// Round 15
// 199.395 us; speedup vs baseline: 1.0214x; 1.0214x over previous
//
#include <hip/hip_runtime.h>
#include <math.h>

#define B_ 2
#define S_ 4096
#define D_ 1024
#define M_ 4
#define N_ (B_*S_)   // 8192 rows
#define EPS 1e-6f

typedef unsigned short u16;
typedef __bf16 bf16x8 __attribute__((ext_vector_type(8)));
typedef float  f32x4  __attribute__((ext_vector_type(4)));

__device__ __forceinline__ float elu1(float x) {
    // F.elu(x)+1 : x>0 -> x+1 ; x<=0 -> exp(x)
    return x > 0.0f ? x + 1.0f : __expf(x);
}

// fp32 -> bf16 round-to-nearest-even (finite inputs)
__device__ __forceinline__ u16 f2b(float f) {
    unsigned int u = __float_as_uint(f);
    return (u16)((u + 0x7FFFu + ((u >> 16) & 1u)) >> 16);
}

// async global->LDS, 16B per lane; LDS dest = wave-uniform base + lane*16
#define GLDS16(gp, lp) __builtin_amdgcn_global_load_lds( \
    (const __attribute__((address_space(1))) void*)(gp), \
    (__attribute__((address_space(3))) void*)(lp), 16, 0, 0)

// ---------------- per-row Q stats: qnorm[m,r] + sigma(Q) bf16.
// Blocks 0..31 also zero knorm (8192) / colsum (1024) — consumed only by the
// LATER prep_k kernel, so no ordering hazard.
__global__ __launch_bounds__(256) void k1_stats(
    const float* __restrict__ Q, const float* __restrict__ mnorm,
    float* __restrict__ qnorm,   // (M,N)
    u16* __restrict__ sQ,        // (N,D) bf16
    float* __restrict__ knorm, float* __restrict__ colsum)
{
    int r = blockIdx.x;
    int t = threadIdx.x;
    if (r < 32) {
        knorm[r * 256 + t] = 0.0f;
        if (r < 4) colsum[r * 256 + t] = 0.0f;
    }
    float4 q4 = *(const float4*)(Q + (size_t)r * D_ + t * 4);
    float sq0 = elu1(q4.x), sq1 = elu1(q4.y), sq2 = elu1(q4.z), sq3 = elu1(q4.w);

    uint2 sv;
    sv.x = (unsigned)f2b(sq0) | ((unsigned)f2b(sq1) << 16);
    sv.y = (unsigned)f2b(sq2) | ((unsigned)f2b(sq3) << 16);
    *(uint2*)(sQ + (size_t)r * D_ + t * 4) = sv;

    float vals[M_];
    #pragma unroll
    for (int m = 0; m < M_; ++m) {
        float4 w4 = *(const float4*)(mnorm + m * D_ + t * 4);
        vals[m] = sq0 * w4.x + sq1 * w4.y + sq2 * w4.z + sq3 * w4.w;
    }

    __shared__ float sbuf[M_][4];
    int wave = t >> 6, lane = t & 63;
    #pragma unroll
    for (int i = 0; i < M_; ++i) {
        float v = vals[i];
        #pragma unroll
        for (int off = 32; off > 0; off >>= 1) v += __shfl_down(v, off, 64);
        if (lane == 0) sbuf[i][wave] = v;
    }
    __syncthreads();
    if (t == 0) {
        #pragma unroll
        for (int m = 0; m < M_; ++m)
            qnorm[(size_t)m * N_ + r] = sbuf[m][0] + sbuf[m][1] + sbuf[m][2] + sbuf[m][3];
    }
}

// ---------------- sigma(K): bf16 row-major + bf16 transposed + colsum + knorm (one K pass)
__global__ __launch_bounds__(256) void prep_k(
    const float* __restrict__ K, const float* __restrict__ mnorm,
    u16* __restrict__ sk, u16* __restrict__ skT,
    float* __restrict__ colsum, float* __restrict__ knorm)
{
    __shared__ float tile[64][65];
    __shared__ float mn0[64];
    int r0 = blockIdx.x * 64;
    int d0 = blockIdx.y * 64;
    int t = threadIdx.x;
    int rr = t >> 4, c4 = (t & 15) * 4;
    if (t >= 128 && t < 192) mn0[t - 128] = mnorm[d0 + (t - 128)];
    #pragma unroll
    for (int i = 0; i < 4; ++i) {
        int rri = rr + i * 16;
        float4 k4 = *(const float4*)(K + (size_t)(r0 + rri) * D_ + d0 + c4);
        float e0 = elu1(k4.x), e1 = elu1(k4.y), e2 = elu1(k4.z), e3 = elu1(k4.w);
        uint2 v; v.x = (unsigned)f2b(e0) | ((unsigned)f2b(e1) << 16);
        v.y = (unsigned)f2b(e2) | ((unsigned)f2b(e3) << 16);
        *(uint2*)(sk + (size_t)(r0 + rri) * D_ + d0 + c4) = v;
        tile[rri][c4 + 0] = e0; tile[rri][c4 + 1] = e1;
        tile[rri][c4 + 2] = e2; tile[rri][c4 + 3] = e3;
    }
    __syncthreads();
    #pragma unroll
    for (int i = 0; i < 4; ++i) {
        int dd = rr + i * 16;
        float v0 = tile[c4 + 0][dd], v1 = tile[c4 + 1][dd];
        float v2 = tile[c4 + 2][dd], v3 = tile[c4 + 3][dd];
        uint2 v; v.x = (unsigned)f2b(v0) | ((unsigned)f2b(v1) << 16);
        v.y = (unsigned)f2b(v2) | ((unsigned)f2b(v3) << 16);
        *(uint2*)(skT + (size_t)(d0 + dd) * N_ + r0 + c4) = v;
    }
    if (t < 64) {               // wave 0: knorm partial dot with mnorm row 0
        float s = 0.0f;
        #pragma unroll
        for (int j = 0; j < 64; ++j) s += tile[t][j] * mn0[j];
        atomicAdd(&knorm[r0 + t], s);
    } else if (t < 128) {       // wave 1: column sums
        int c = t - 64;
        float s = 0.0f;
        #pragma unroll
        for (int j = 0; j < 64; ++j) s += tile[j][c];
        atomicAdd(&colsum[d0 + c], s);
    }
}

// ---------------- memories (4,1024,1024) -> MemT bf16 [e][m*1024+d].
// m==0 blocks also copy the raw fp32 Mem0 tile into out_mem.
__global__ __launch_bounds__(256) void prep_memT(
    const float* __restrict__ Mem, u16* __restrict__ MemT,
    float* __restrict__ out_mem)
{
    __shared__ float tile[64][65];
    int m = blockIdx.z;
    int e0 = blockIdx.x * 64, d0 = blockIdx.y * 64;
    int t = threadIdx.x, rr = t >> 4, c4 = (t & 15) * 4;
    #pragma unroll
    for (int i = 0; i < 4; ++i) {
        int dd = rr + i * 16;
        float4 v4 = *(const float4*)(Mem + ((size_t)m * D_ + d0 + dd) * D_ + e0 + c4);
        tile[dd][c4 + 0] = v4.x; tile[dd][c4 + 1] = v4.y;
        tile[dd][c4 + 2] = v4.z; tile[dd][c4 + 3] = v4.w;
        if (m == 0)
            *(float4*)(out_mem + (size_t)(d0 + dd) * D_ + e0 + c4) = v4;
    }
    __syncthreads();
    #pragma unroll
    for (int i = 0; i < 4; ++i) {
        int ee = rr + i * 16;
        float v0 = tile[c4 + 0][ee], v1 = tile[c4 + 1][ee];
        float v2 = tile[c4 + 2][ee], v3 = tile[c4 + 3][ee];
        uint2 v; v.x = (unsigned)f2b(v0) | ((unsigned)f2b(v1) << 16);
        v.y = (unsigned)f2b(v2) | ((unsigned)f2b(v3) << 16);
        *(uint2*)(MemT + (size_t)(e0 + ee) * (M_ * D_) + m * D_ + d0 + c4) = v;
    }
}

// ---------------- weights: |mnorm| reduce + relsum (from qnorm) + softmax over m
__global__ __launch_bounds__(512) void k2_weights(
    const float* __restrict__ mnorm, const float* __restrict__ qnorm,
    float* __restrict__ weights)
{
    __shared__ float sbuf[12][8];
    int t = threadIdx.x, wave = t >> 6, lane = t & 63;
    float vals[12];
    #pragma unroll
    for (int m = 0; m < M_; ++m) {
        float v = 0.0f;
        for (int d = t; d < D_; d += 512) v += fabsf(mnorm[m * D_ + d]);
        vals[m] = v;
    }
    #pragma unroll
    for (int mb = 0; mb < M_ * B_; ++mb) {
        int m = mb >> 1, b = mb & 1;
        const float4* p = (const float4*)(qnorm + (size_t)m * N_ + (size_t)b * S_);
        float v = 0.0f;
        for (int i = t; i < S_ / 4; i += 512) {
            float4 x = p[i];
            v += x.x + x.y + x.z + x.w;
        }
        vals[4 + mb] = v;
    }
    #pragma unroll
    for (int i = 0; i < 12; ++i) {
        float v = vals[i];
        #pragma unroll
        for (int off = 32; off > 0; off >>= 1) v += __shfl_down(v, off, 64);
        if (lane == 0) sbuf[i][wave] = v;
    }
    __syncthreads();
    if (t == 0) {
        bool empty[M_]; bool all_empty = true;
        float relsum[M_ * B_];
        #pragma unroll
        for (int m = 0; m < M_; ++m) {
            float sa = 0.0f;
            #pragma unroll
            for (int w = 0; w < 8; ++w) sa += sbuf[m][w];
            empty[m] = (sa < EPS);
            all_empty = all_empty && empty[m];
        }
        #pragma unroll
        for (int mb = 0; mb < M_ * B_; ++mb) {
            float sv = 0.0f;
            #pragma unroll
            for (int w = 0; w < 8; ++w) sv += sbuf[4 + mb][w];
            relsum[mb] = sv;
        }
        for (int b = 0; b < B_; ++b) {
            float rel[M_]; float mx = -3.0e38f;
            #pragma unroll
            for (int m = 0; m < M_; ++m) {
                rel[m] = empty[m] ? -1.0e30f : relsum[m * B_ + b] * (1.0f / (float)S_);
                mx = fmaxf(mx, rel[m]);
            }
            float se = 0.0f;
            #pragma unroll
            for (int m = 0; m < M_; ++m) { rel[m] = __expf(rel[m] - mx); se += rel[m]; }
            #pragma unroll
            for (int m = 0; m < M_; ++m) {
                float wv = rel[m] / se;
                if (empty[m] || all_empty) wv = 0.0f;
                weights[m * B_ + b] = wv;
            }
        }
    }
}

// ---------------- ratio planes for in-accumulator c-folding + new_memory_norm output
__global__ __launch_bounds__(256) void k2_cvec(
    const float* __restrict__ qnorm, const float* __restrict__ weights,
    const float* __restrict__ mnorm, const float* __restrict__ colsum,
    float* __restrict__ ratT, float* __restrict__ norm_out)
{
    int g = blockIdx.x * 256 + threadIdx.x;
    if (g < N_) {
        int b = g / S_;
        float cs[M_];
        #pragma unroll
        for (int m = 0; m < M_; ++m)
            cs[m] = fmaxf(weights[m * B_ + b] / fmaxf(qnorm[(size_t)m * N_ + g], EPS), 1e-20f);
        ratT[0 * (size_t)N_ + g] = cs[0] / cs[1];
        ratT[1 * (size_t)N_ + g] = cs[1] / cs[2];
        ratT[2 * (size_t)N_ + g] = cs[2] / cs[3];
        ratT[3 * (size_t)N_ + g] = cs[3];
    }
    if (g < D_) norm_out[g] = mnorm[g] + colsum[g] * (1.0f / (float)B_);
}

// ================= 128²/4-wave 2-phase GEMM core (best measured: R13 config) =================
// acc += A[rb..rb+128][ak0..] * B[cb..cb+128][bk0..]^T, k-contig bf16. BK=32.
// 4 waves (2x2), per wave 64x64 = 4x4 frags of 16x16x32 MFMA. Double-buffered
// LDS (2x8KB/operand), 4 blocks/CU. Caller zeros acc (segments accumulate).
// XOR slot swizzle on global source (glds writes linearly) re-applied on ds_read.
// Trailing lgkmcnt+barrier makes back-to-back segments WAR-safe on the LDS bufs.
// SETTLED: 2-phase drain + 4 small blocks/CU beats all tested alternatives
// (R10 8-wave drain-0, R11 8-wave counted-vmcnt, R14 4-wave depth-2@3blk) —
// the drain stall is absorbed by inter-block TLP, which the variants trade away.
__device__ __forceinline__ void tile_mma(
    const u16* Asb, const u16* Bsb, int aoff, int boff, f32x4 (&acc)[4][4])
{
    bf16x8 af[4], bf[4];
    #pragma unroll
    for (int i = 0; i < 4; ++i) {
        af[i] = *(const bf16x8*)((const char*)Asb + aoff + i * 1024);
        bf[i] = *(const bf16x8*)((const char*)Bsb + boff + i * 1024);
    }
    #pragma unroll
    for (int mi = 0; mi < 4; ++mi)
        #pragma unroll
        for (int ni = 0; ni < 4; ++ni)
            acc[mi][ni] = __builtin_amdgcn_mfma_f32_16x16x32_bf16(
                af[mi], bf[ni], acc[mi][ni], 0, 0, 0);
}

__device__ __forceinline__ void gemm_seg(
    u16* As, u16* Bs,   // each [2][4096] u16 in LDS
    const u16* __restrict__ A, int lda, int ak0,
    const u16* __restrict__ B, int ldb, int bk0,
    int rb, int cb, int klen,
    f32x4 (&acc)[4][4])
{
    const int tid  = threadIdx.x;
    const int lane = tid & 63;
    const int wid  = tid >> 6;
    const int wr   = wid >> 1, wc = wid & 1;
    const int r15  = lane & 15;

    const int srow0 = (wid * 2 + 0) * 16 + (lane >> 2);
    const int srow1 = (wid * 2 + 1) * 16 + (lane >> 2);
    const int sg    = ((lane & 3) ^ ((lane >> 3) & 3)) * 8;
    const u16* Ag0 = A + (size_t)(rb + srow0) * lda + ak0 + sg;
    const u16* Ag1 = A + (size_t)(rb + srow1) * lda + ak0 + sg;
    const u16* Bg0 = B + (size_t)(cb + srow0) * ldb + bk0 + sg;
    const u16* Bg1 = B + (size_t)(cb + srow1) * ldb + bk0 + sg;
    const int lo0 = (wid * 2 + 0) * 512;
    const int lo1 = (wid * 2 + 1) * 512;

    const int xo   = (((lane >> 4) ^ ((r15 >> 1) & 3)) * 16);
    const int aoff = (wr * 64 + r15) * 64 + xo;
    const int boff = (wc * 64 + r15) * 64 + xo;

    GLDS16(Ag0, As + lo0);
    GLDS16(Ag1, As + lo1);
    GLDS16(Bg0, Bs + lo0);
    GLDS16(Bg1, Bs + lo1);
    asm volatile("s_waitcnt vmcnt(0)" ::: "memory");
    __builtin_amdgcn_s_barrier();

    int cur = 0;
    for (int kt = 32; kt < klen; kt += 32) {
        int nxt = cur ^ 1;
        GLDS16(Ag0 + kt, As + nxt * 4096 + lo0);
        GLDS16(Ag1 + kt, As + nxt * 4096 + lo1);
        GLDS16(Bg0 + kt, Bs + nxt * 4096 + lo0);
        GLDS16(Bg1 + kt, Bs + nxt * 4096 + lo1);
        tile_mma(As + cur * 4096, Bs + cur * 4096, aoff, boff, acc);
        asm volatile("s_waitcnt vmcnt(0) lgkmcnt(0)" ::: "memory");
        __builtin_amdgcn_s_barrier();
        cur = nxt;
    }
    tile_mma(As + cur * 4096, Bs + cur * 4096, aoff, boff, acc);
    asm volatile("s_waitcnt lgkmcnt(0)" ::: "memory");
    __builtin_amdgcn_s_barrier();
}

// ---------------- epilogues
__device__ __forceinline__ void epi_out(
    f32x4 (&acc)[4][4], float* __restrict__ out, int rb, int cb)
{
    int lane = threadIdx.x & 63, wid = threadIdx.x >> 6;
    int wr = wid >> 1, wc = wid & 1, r15 = lane & 15;
    #pragma unroll
    for (int mi = 0; mi < 4; ++mi) {
        int row0 = rb + wr * 64 + mi * 16 + (lane >> 4) * 4;
        #pragma unroll
        for (int ni = 0; ni < 4; ++ni) {
            int col = cb + wc * 64 + ni * 16 + r15;
            #pragma unroll
            for (int r = 0; r < 4; ++r)
                out[(size_t)(row0 + r) * D_ + col] = acc[mi][ni][r];
        }
    }
}

__device__ __forceinline__ void epi_delta(
    f32x4 (&acc)[4][4], const float* __restrict__ V,
    const float* __restrict__ knorm, u16* __restrict__ deltaT,
    int rb, int cb)
{
    int lane = threadIdx.x & 63, wid = threadIdx.x >> 6;
    int wr = wid >> 1, wc = wid & 1, r15 = lane & 15;
    #pragma unroll
    for (int mi = 0; mi < 4; ++mi) {
        int row0 = rb + wr * 64 + mi * 16 + (lane >> 4) * 4;
        float inv[4];
        #pragma unroll
        for (int r = 0; r < 4; ++r) inv[r] = 1.0f / fmaxf(knorm[row0 + r], EPS);
        #pragma unroll
        for (int ni = 0; ni < 4; ++ni) {
            int col = cb + wc * 64 + ni * 16 + r15;
            float dv[4];
            #pragma unroll
            for (int r = 0; r < 4; ++r)
                dv[r] = V[(size_t)(row0 + r) * D_ + col] - acc[mi][ni][r] * inv[r];
            uint2 pv;
            pv.x = (unsigned)f2b(dv[0]) | ((unsigned)f2b(dv[1]) << 16);
            pv.y = (unsigned)f2b(dv[2]) | ((unsigned)f2b(dv[3]) << 16);
            *(uint2*)(deltaT + (size_t)col * N_ + row0) = pv;  // lanes 0/16/32/48 coalesce
        }
    }
}

// ---------------- FUSED retrieve + delta, ROW-PANEL-per-XCD mapping (R13-proven:
// FETCH 350->81MB, g34 124us). XCD x owns output-row panel by in [8x,8x+8) x all
// bx. Retrieve: A = sigma(Q) in 4 K-segments; c_m folded into the accumulator
// between segments (acc *= ratT plane) -> no Ac materialization.
__global__ __launch_bounds__(256, 4) void g34_fused(
    const u16* __restrict__ sQ, const u16* __restrict__ MemT,
    const u16* __restrict__ sk, const float* __restrict__ V,
    const float* __restrict__ knorm, const float* __restrict__ ratT,
    float* __restrict__ out, u16* __restrict__ deltaT)
{
    __shared__ u16 As[2 * 4096];
    __shared__ u16 Bs[2 * 4096];
    int hw = blockIdx.x;
    int x   = hw & 7;            // XCD (HW round-robins blockIdx % 8)
    int l   = hw >> 3;           // [0,128) within XCD
    int z   = l >> 6;            // 0: retrieve (hw<512), 1: delta
    int idx = l & 63;
    int by  = x * 8 + (idx >> 3);  // XCD-owned row-panel range
    int bx  = idx & 7;
    int rb = by * 128, cb = bx * 128;
    int lane = threadIdx.x & 63, wid = threadIdx.x >> 6;
    int wr = wid >> 1;
    f32x4 acc[4][4];
    #pragma unroll
    for (int i = 0; i < 4; ++i)
        #pragma unroll
        for (int j = 0; j < 4; ++j) {
            f32x4 zz = {0.0f, 0.0f, 0.0f, 0.0f};
            acc[i][j] = zz;
        }
    if (z == 0) {
        #pragma unroll 1
        for (int m = 0; m < M_; ++m) {
            gemm_seg(As, Bs, sQ, D_, 0, MemT, M_ * D_, m * D_, rb, cb, D_, acc);
            const float* rp = ratT + (size_t)m * N_;
            #pragma unroll
            for (int mi = 0; mi < 4; ++mi) {
                int row0 = rb + wr * 64 + mi * 16 + (lane >> 4) * 4;
                float4 rt = *(const float4*)(rp + row0);
                #pragma unroll
                for (int ni = 0; ni < 4; ++ni) {
                    acc[mi][ni][0] *= rt.x; acc[mi][ni][1] *= rt.y;
                    acc[mi][ni][2] *= rt.z; acc[mi][ni][3] *= rt.w;
                }
            }
        }
        epi_out(acc, out, rb, cb);
    } else {
        gemm_seg(As, Bs, sk, D_, 0, MemT, M_ * D_, 0, rb, cb, D_, acc);
        epi_delta(acc, V, knorm, deltaT, rb, cb);
    }
}

// ---------------- update: out_mem(D,D) += (skT * deltaT^T)/N, split-K=8, fp32 atomics.
// K-SLICE-per-XCD mapping (kept from R14 — the one component that helped):
// kz = hw&7 == XCD -> each XCD reads only its skT/deltaT k-slice (2+2MB,
// L2-resident) instead of re-streaming 32MB. Core = R13's 2-buffer gemm_seg.
#define KSPLIT 8
__global__ __launch_bounds__(256, 4) void g5_update(
    const u16* __restrict__ skT, const u16* __restrict__ deltaT,
    float* __restrict__ memout)
{
    __shared__ u16 As[2 * 4096];
    __shared__ u16 Bs[2 * 4096];
    f32x4 acc[4][4];
    #pragma unroll
    for (int i = 0; i < 4; ++i)
        #pragma unroll
        for (int j = 0; j < 4; ++j) {
            f32x4 zz = {0.0f, 0.0f, 0.0f, 0.0f};
            acc[i][j] = zz;
        }
    int hw = blockIdx.x;
    int kz = hw & 7;             // XCD owns one k-slice
    int l  = hw >> 3;            // [0,64)
    int by = l >> 3, bx = l & 7;
    int rb = by * 128, cb = bx * 128;
    int k0 = kz * (N_ / KSPLIT);
    gemm_seg(As, Bs, skT, N_, k0, deltaT, N_, k0, rb, cb, N_ / KSPLIT, acc);
    int lane = threadIdx.x & 63, wid = threadIdx.x >> 6;
    int wr = wid >> 1, wc = wid & 1, r15 = lane & 15;
    const float sc = 1.0f / (float)N_;
    #pragma unroll
    for (int mi = 0; mi < 4; ++mi) {
        int row0 = rb + wr * 64 + mi * 16 + (lane >> 4) * 4;
        #pragma unroll
        for (int ni = 0; ni < 4; ++ni) {
            int col = cb + wc * 64 + ni * 16 + r15;
            #pragma unroll
            for (int r = 0; r < 4; ++r)
                atomicAdd(memout + (size_t)(row0 + r) * D_ + col, acc[mi][ni][r] * sc);
        }
    }
}

extern "C" void kernel_launch(void* const* d_in, const int* in_sizes, int n_in,
                              void* d_out, int out_size, void* d_ws, size_t ws_size,
                              hipStream_t stream) {
    const float* Q     = (const float*)d_in[0];
    const float* K     = (const float*)d_in[1];
    const float* V     = (const float*)d_in[2];
    const float* Mem   = (const float*)d_in[3];
    const float* Mnorm = (const float*)d_in[4];

    float* out      = (float*)d_out;
    float* out_mem  = out + (size_t)N_ * D_;        // D*D
    float* out_norm = out_mem + (size_t)D_ * D_;    // D

    // ---- workspace layout (needs ~74MB; ws >= 121MB proven in prior rounds) ----
    // [0,1MB):   fp32 stats: qnorm(M*N) knorm(N) colsum(D) weights(8) ratT(4*N)
    // [1,9MB):   MemT  bf16 [1024][4096]
    // [9,25MB):  sk    bf16 [8192][1024]
    // [25,41MB): skT   bf16 [1024][8192]
    // [41,57MB): sQ    bf16 [8192][1024]
    // [57,73MB): deltaT bf16 [1024][8192]
    char* wsb = (char*)d_ws;
    float* qnorm   = (float*)wsb;                   // 32768
    float* knorm   = qnorm + (size_t)M_ * N_;       // 8192
    float* colsum  = knorm + N_;                    // 1024
    float* weights = colsum + D_;                   // 8
    float* ratT    = weights + M_ * B_;             // 4*N = 32768 (16B aligned)
    u16* MemT   = (u16*)(wsb + (size_t)1  * (1 << 20));
    u16* sk     = (u16*)(wsb + (size_t)9  * (1 << 20));
    u16* skT    = (u16*)(wsb + (size_t)25 * (1 << 20));
    u16* sQ     = (u16*)(wsb + (size_t)41 * (1 << 20));
    u16* deltaT = (u16*)(wsb + (size_t)57 * (1 << 20));

    hipLaunchKernelGGL(k1_stats, dim3(N_), dim3(256), 0, stream, Q, Mnorm, qnorm, sQ, knorm, colsum);
    hipLaunchKernelGGL(prep_k, dim3(128, 16), dim3(256), 0, stream, K, Mnorm, sk, skT, colsum, knorm);
    hipLaunchKernelGGL(prep_memT, dim3(16, 16, 4), dim3(256), 0, stream, Mem, MemT, out_mem);
    hipLaunchKernelGGL(k2_weights, dim3(1), dim3(512), 0, stream, Mnorm, qnorm, weights);
    hipLaunchKernelGGL(k2_cvec, dim3(32), dim3(256), 0, stream, qnorm, weights, Mnorm, colsum, ratT, out_norm);
    hipLaunchKernelGGL(g34_fused, dim3(1024), dim3(256), 0, stream,
                       sQ, MemT, sk, V, knorm, ratT, out, deltaT);
    hipLaunchKernelGGL(g5_update, dim3(512), dim3(256), 0, stream, skT, deltaT, out_mem);
}

// Round 16
// 199.294 us; speedup vs baseline: 1.0219x; 1.0005x over previous
//
#include <hip/hip_runtime.h>
#include <math.h>

#define B_ 2
#define S_ 4096
#define D_ 1024
#define M_ 4
#define N_ (B_*S_)   // 8192 rows
#define EPS 1e-6f

typedef unsigned short u16;
typedef __bf16 bf16x8 __attribute__((ext_vector_type(8)));
typedef float  f32x4  __attribute__((ext_vector_type(4)));

__device__ __forceinline__ float elu1(float x) {
    // F.elu(x)+1 : x>0 -> x+1 ; x<=0 -> exp(x)
    return x > 0.0f ? x + 1.0f : __expf(x);
}

// fp32 -> bf16 round-to-nearest-even (finite inputs)
__device__ __forceinline__ u16 f2b(float f) {
    unsigned int u = __float_as_uint(f);
    return (u16)((u + 0x7FFFu + ((u >> 16) & 1u)) >> 16);
}

// async global->LDS, 16B per lane; LDS dest = wave-uniform base + lane*16
#define GLDS16(gp, lp) __builtin_amdgcn_global_load_lds( \
    (const __attribute__((address_space(1))) void*)(gp), \
    (__attribute__((address_space(3))) void*)(lp), 16, 0, 0)

// ---------------- per-row Q stats: qnorm[m,r] + sigma(Q) bf16.
// Blocks 0..31 also zero knorm (8192) / colsum (1024) — consumed only by the
// LATER prep_km kernel, so no ordering hazard.
__global__ __launch_bounds__(256) void k1_stats(
    const float* __restrict__ Q, const float* __restrict__ mnorm,
    float* __restrict__ qnorm,   // (M,N)
    u16* __restrict__ sQ,        // (N,D) bf16
    float* __restrict__ knorm, float* __restrict__ colsum)
{
    int r = blockIdx.x;
    int t = threadIdx.x;
    if (r < 32) {
        knorm[r * 256 + t] = 0.0f;
        if (r < 4) colsum[r * 256 + t] = 0.0f;
    }
    float4 q4 = *(const float4*)(Q + (size_t)r * D_ + t * 4);
    float sq0 = elu1(q4.x), sq1 = elu1(q4.y), sq2 = elu1(q4.z), sq3 = elu1(q4.w);

    uint2 sv;
    sv.x = (unsigned)f2b(sq0) | ((unsigned)f2b(sq1) << 16);
    sv.y = (unsigned)f2b(sq2) | ((unsigned)f2b(sq3) << 16);
    *(uint2*)(sQ + (size_t)r * D_ + t * 4) = sv;

    float vals[M_];
    #pragma unroll
    for (int m = 0; m < M_; ++m) {
        float4 w4 = *(const float4*)(mnorm + m * D_ + t * 4);
        vals[m] = sq0 * w4.x + sq1 * w4.y + sq2 * w4.z + sq3 * w4.w;
    }

    __shared__ float sbuf[M_][4];
    int wave = t >> 6, lane = t & 63;
    #pragma unroll
    for (int i = 0; i < M_; ++i) {
        float v = vals[i];
        #pragma unroll
        for (int off = 32; off > 0; off >>= 1) v += __shfl_down(v, off, 64);
        if (lane == 0) sbuf[i][wave] = v;
    }
    __syncthreads();
    if (t == 0) {
        #pragma unroll
        for (int m = 0; m < M_; ++m)
            qnorm[(size_t)m * N_ + r] = sbuf[m][0] + sbuf[m][1] + sbuf[m][2] + sbuf[m][3];
    }
}

// ---------------- MERGED prep: blocks [0,2048) = sigma(K) pass (sk, skT,
// colsum, knorm); blocks [2048,3072) = memories -> MemT bf16 (+ Mem0 copy to
// out_mem). The two halves are data-independent; merging removes a launch gap
// and lets the small memT half fill CU slots alongside the K pass.
__global__ __launch_bounds__(256) void prep_km(
    const float* __restrict__ K, const float* __restrict__ mnorm,
    const float* __restrict__ Mem,
    u16* __restrict__ sk, u16* __restrict__ skT,
    float* __restrict__ colsum, float* __restrict__ knorm,
    u16* __restrict__ MemT, float* __restrict__ out_mem)
{
    __shared__ float tile[64][65];
    __shared__ float mn0[64];
    int i = blockIdx.x;
    int t = threadIdx.x;
    int rr = t >> 4, c4 = (t & 15) * 4;
    if (i < 2048) {
        // ---- sigma(K) half (was prep_k, grid 128x16)
        int r0 = (i & 127) * 64;
        int d0 = (i >> 7) * 64;
        if (t >= 128 && t < 192) mn0[t - 128] = mnorm[d0 + (t - 128)];
        #pragma unroll
        for (int s = 0; s < 4; ++s) {
            int rri = rr + s * 16;
            float4 k4 = *(const float4*)(K + (size_t)(r0 + rri) * D_ + d0 + c4);
            float e0 = elu1(k4.x), e1 = elu1(k4.y), e2 = elu1(k4.z), e3 = elu1(k4.w);
            uint2 v; v.x = (unsigned)f2b(e0) | ((unsigned)f2b(e1) << 16);
            v.y = (unsigned)f2b(e2) | ((unsigned)f2b(e3) << 16);
            *(uint2*)(sk + (size_t)(r0 + rri) * D_ + d0 + c4) = v;
            tile[rri][c4 + 0] = e0; tile[rri][c4 + 1] = e1;
            tile[rri][c4 + 2] = e2; tile[rri][c4 + 3] = e3;
        }
        __syncthreads();
        #pragma unroll
        for (int s = 0; s < 4; ++s) {
            int dd = rr + s * 16;
            float v0 = tile[c4 + 0][dd], v1 = tile[c4 + 1][dd];
            float v2 = tile[c4 + 2][dd], v3 = tile[c4 + 3][dd];
            uint2 v; v.x = (unsigned)f2b(v0) | ((unsigned)f2b(v1) << 16);
            v.y = (unsigned)f2b(v2) | ((unsigned)f2b(v3) << 16);
            *(uint2*)(skT + (size_t)(d0 + dd) * N_ + r0 + c4) = v;
        }
        if (t < 64) {               // wave 0: knorm partial dot with mnorm row 0
            float s = 0.0f;
            #pragma unroll
            for (int j = 0; j < 64; ++j) s += tile[t][j] * mn0[j];
            atomicAdd(&knorm[r0 + t], s);
        } else if (t < 128) {       // wave 1: column sums
            int c = t - 64;
            float s = 0.0f;
            #pragma unroll
            for (int j = 0; j < 64; ++j) s += tile[j][c];
            atomicAdd(&colsum[d0 + c], s);
        }
    } else {
        // ---- memories half (was prep_memT, grid 16x16x4)
        int j = i - 2048;
        int m  = j >> 8;
        int e0 = ((j >> 4) & 15) * 64;
        int d0 = (j & 15) * 64;
        #pragma unroll
        for (int s = 0; s < 4; ++s) {
            int dd = rr + s * 16;
            float4 v4 = *(const float4*)(Mem + ((size_t)m * D_ + d0 + dd) * D_ + e0 + c4);
            tile[dd][c4 + 0] = v4.x; tile[dd][c4 + 1] = v4.y;
            tile[dd][c4 + 2] = v4.z; tile[dd][c4 + 3] = v4.w;
            if (m == 0)
                *(float4*)(out_mem + (size_t)(d0 + dd) * D_ + e0 + c4) = v4;
        }
        __syncthreads();
        #pragma unroll
        for (int s = 0; s < 4; ++s) {
            int ee = rr + s * 16;
            float v0 = tile[c4 + 0][ee], v1 = tile[c4 + 1][ee];
            float v2 = tile[c4 + 2][ee], v3 = tile[c4 + 3][ee];
            uint2 v; v.x = (unsigned)f2b(v0) | ((unsigned)f2b(v1) << 16);
            v.y = (unsigned)f2b(v2) | ((unsigned)f2b(v3) << 16);
            *(uint2*)(MemT + (size_t)(e0 + ee) * (M_ * D_) + m * D_ + d0 + c4) = v;
        }
    }
}

// ---------------- MERGED weights + cvec: each of 32 blocks redundantly
// recomputes the 12 reductions (~150KB of L2-hot reads, fixed order -> result
// bit-identical across blocks), derives the softmax weights in-block, then does
// its 256-element slice of the ratio planes + norm_out. Replaces the 1-block
// k2_weights launch (255 CUs idle) + a launch gap.
__global__ __launch_bounds__(256) void k2_wc(
    const float* __restrict__ mnorm, const float* __restrict__ qnorm,
    const float* __restrict__ colsum,
    float* __restrict__ ratT, float* __restrict__ norm_out)
{
    __shared__ float sbuf[12][4];
    __shared__ float wsh[M_ * B_];
    int t = threadIdx.x, wave = t >> 6, lane = t & 63;
    float vals[12];
    #pragma unroll
    for (int m = 0; m < M_; ++m) {
        float v = 0.0f;
        for (int d = t; d < D_; d += 256) v += fabsf(mnorm[m * D_ + d]);
        vals[m] = v;
    }
    #pragma unroll
    for (int mb = 0; mb < M_ * B_; ++mb) {
        int m = mb >> 1, b = mb & 1;
        const float4* p = (const float4*)(qnorm + (size_t)m * N_ + (size_t)b * S_);
        float v = 0.0f;
        for (int i = t; i < S_ / 4; i += 256) {
            float4 x = p[i];
            v += x.x + x.y + x.z + x.w;
        }
        vals[4 + mb] = v;
    }
    #pragma unroll
    for (int i = 0; i < 12; ++i) {
        float v = vals[i];
        #pragma unroll
        for (int off = 32; off > 0; off >>= 1) v += __shfl_down(v, off, 64);
        if (lane == 0) sbuf[i][wave] = v;
    }
    __syncthreads();
    if (t == 0) {
        bool empty[M_]; bool all_empty = true;
        float relsum[M_ * B_];
        #pragma unroll
        for (int m = 0; m < M_; ++m) {
            float sa = sbuf[m][0] + sbuf[m][1] + sbuf[m][2] + sbuf[m][3];
            empty[m] = (sa < EPS);
            all_empty = all_empty && empty[m];
        }
        #pragma unroll
        for (int mb = 0; mb < M_ * B_; ++mb)
            relsum[mb] = sbuf[4 + mb][0] + sbuf[4 + mb][1] + sbuf[4 + mb][2] + sbuf[4 + mb][3];
        for (int b = 0; b < B_; ++b) {
            float rel[M_]; float mx = -3.0e38f;
            #pragma unroll
            for (int m = 0; m < M_; ++m) {
                rel[m] = empty[m] ? -1.0e30f : relsum[m * B_ + b] * (1.0f / (float)S_);
                mx = fmaxf(mx, rel[m]);
            }
            float se = 0.0f;
            #pragma unroll
            for (int m = 0; m < M_; ++m) { rel[m] = __expf(rel[m] - mx); se += rel[m]; }
            #pragma unroll
            for (int m = 0; m < M_; ++m) {
                float wv = rel[m] / se;
                if (empty[m] || all_empty) wv = 0.0f;
                wsh[m * B_ + b] = wv;
            }
        }
    }
    __syncthreads();
    // ---- cvec slice: ratio planes + norm_out
    int g = blockIdx.x * 256 + t;      // 32 blocks x 256 = N_
    int b = g / S_;
    float cs[M_];
    #pragma unroll
    for (int m = 0; m < M_; ++m)
        cs[m] = fmaxf(wsh[m * B_ + b] / fmaxf(qnorm[(size_t)m * N_ + g], EPS), 1e-20f);
    ratT[0 * (size_t)N_ + g] = cs[0] / cs[1];
    ratT[1 * (size_t)N_ + g] = cs[1] / cs[2];
    ratT[2 * (size_t)N_ + g] = cs[2] / cs[3];
    ratT[3 * (size_t)N_ + g] = cs[3];
    if (g < D_) norm_out[g] = mnorm[g] + colsum[g] * (1.0f / (float)B_);
}

// ================= 128²/4-wave 2-phase GEMM core (best measured: R13/R15 config) =================
// acc += A[rb..rb+128][ak0..] * B[cb..cb+128][bk0..]^T, k-contig bf16. BK=32.
// 4 waves (2x2), per wave 64x64 = 4x4 frags of 16x16x32 MFMA. Double-buffered
// LDS (2x8KB/operand), 4 blocks/CU. Caller zeros acc (segments accumulate).
// XOR slot swizzle on global source (glds writes linearly) re-applied on ds_read.
// Trailing lgkmcnt+barrier makes back-to-back segments WAR-safe on the LDS bufs.
// SETTLED: 2-phase drain + 4 small blocks/CU beats all tested alternatives
// (R10 8-wave drain-0, R11 8-wave counted-vmcnt, R14 4-wave depth-2@3blk) —
// the drain stall is absorbed by inter-block TLP, which the variants trade away.
__device__ __forceinline__ void tile_mma(
    const u16* Asb, const u16* Bsb, int aoff, int boff, f32x4 (&acc)[4][4])
{
    bf16x8 af[4], bf[4];
    #pragma unroll
    for (int i = 0; i < 4; ++i) {
        af[i] = *(const bf16x8*)((const char*)Asb + aoff + i * 1024);
        bf[i] = *(const bf16x8*)((const char*)Bsb + boff + i * 1024);
    }
    #pragma unroll
    for (int mi = 0; mi < 4; ++mi)
        #pragma unroll
        for (int ni = 0; ni < 4; ++ni)
            acc[mi][ni] = __builtin_amdgcn_mfma_f32_16x16x32_bf16(
                af[mi], bf[ni], acc[mi][ni], 0, 0, 0);
}

__device__ __forceinline__ void gemm_seg(
    u16* As, u16* Bs,   // each [2][4096] u16 in LDS
    const u16* __restrict__ A, int lda, int ak0,
    const u16* __restrict__ B, int ldb, int bk0,
    int rb, int cb, int klen,
    f32x4 (&acc)[4][4])
{
    const int tid  = threadIdx.x;
    const int lane = tid & 63;
    const int wid  = tid >> 6;
    const int wr   = wid >> 1, wc = wid & 1;
    const int r15  = lane & 15;

    const int srow0 = (wid * 2 + 0) * 16 + (lane >> 2);
    const int srow1 = (wid * 2 + 1) * 16 + (lane >> 2);
    const int sg    = ((lane & 3) ^ ((lane >> 3) & 3)) * 8;
    const u16* Ag0 = A + (size_t)(rb + srow0) * lda + ak0 + sg;
    const u16* Ag1 = A + (size_t)(rb + srow1) * lda + ak0 + sg;
    const u16* Bg0 = B + (size_t)(cb + srow0) * ldb + bk0 + sg;
    const u16* Bg1 = B + (size_t)(cb + srow1) * ldb + bk0 + sg;
    const int lo0 = (wid * 2 + 0) * 512;
    const int lo1 = (wid * 2 + 1) * 512;

    const int xo   = (((lane >> 4) ^ ((r15 >> 1) & 3)) * 16);
    const int aoff = (wr * 64 + r15) * 64 + xo;
    const int boff = (wc * 64 + r15) * 64 + xo;

    GLDS16(Ag0, As + lo0);
    GLDS16(Ag1, As + lo1);
    GLDS16(Bg0, Bs + lo0);
    GLDS16(Bg1, Bs + lo1);
    asm volatile("s_waitcnt vmcnt(0)" ::: "memory");
    __builtin_amdgcn_s_barrier();

    int cur = 0;
    for (int kt = 32; kt < klen; kt += 32) {
        int nxt = cur ^ 1;
        GLDS16(Ag0 + kt, As + nxt * 4096 + lo0);
        GLDS16(Ag1 + kt, As + nxt * 4096 + lo1);
        GLDS16(Bg0 + kt, Bs + nxt * 4096 + lo0);
        GLDS16(Bg1 + kt, Bs + nxt * 4096 + lo1);
        tile_mma(As + cur * 4096, Bs + cur * 4096, aoff, boff, acc);
        asm volatile("s_waitcnt vmcnt(0) lgkmcnt(0)" ::: "memory");
        __builtin_amdgcn_s_barrier();
        cur = nxt;
    }
    tile_mma(As + cur * 4096, Bs + cur * 4096, aoff, boff, acc);
    asm volatile("s_waitcnt lgkmcnt(0)" ::: "memory");
    __builtin_amdgcn_s_barrier();
}

// ---------------- epilogues
__device__ __forceinline__ void epi_out(
    f32x4 (&acc)[4][4], float* __restrict__ out, int rb, int cb)
{
    int lane = threadIdx.x & 63, wid = threadIdx.x >> 6;
    int wr = wid >> 1, wc = wid & 1, r15 = lane & 15;
    #pragma unroll
    for (int mi = 0; mi < 4; ++mi) {
        int row0 = rb + wr * 64 + mi * 16 + (lane >> 4) * 4;
        #pragma unroll
        for (int ni = 0; ni < 4; ++ni) {
            int col = cb + wc * 64 + ni * 16 + r15;
            #pragma unroll
            for (int r = 0; r < 4; ++r)
                out[(size_t)(row0 + r) * D_ + col] = acc[mi][ni][r];
        }
    }
}

__device__ __forceinline__ void epi_delta(
    f32x4 (&acc)[4][4], const float* __restrict__ V,
    const float* __restrict__ knorm, u16* __restrict__ deltaT,
    int rb, int cb)
{
    int lane = threadIdx.x & 63, wid = threadIdx.x >> 6;
    int wr = wid >> 1, wc = wid & 1, r15 = lane & 15;
    #pragma unroll
    for (int mi = 0; mi < 4; ++mi) {
        int row0 = rb + wr * 64 + mi * 16 + (lane >> 4) * 4;
        float inv[4];
        #pragma unroll
        for (int r = 0; r < 4; ++r) inv[r] = 1.0f / fmaxf(knorm[row0 + r], EPS);
        #pragma unroll
        for (int ni = 0; ni < 4; ++ni) {
            int col = cb + wc * 64 + ni * 16 + r15;
            float dv[4];
            #pragma unroll
            for (int r = 0; r < 4; ++r)
                dv[r] = V[(size_t)(row0 + r) * D_ + col] - acc[mi][ni][r] * inv[r];
            uint2 pv;
            pv.x = (unsigned)f2b(dv[0]) | ((unsigned)f2b(dv[1]) << 16);
            pv.y = (unsigned)f2b(dv[2]) | ((unsigned)f2b(dv[3]) << 16);
            *(uint2*)(deltaT + (size_t)col * N_ + row0) = pv;  // lanes 0/16/32/48 coalesce
        }
    }
}

// ---------------- FUSED retrieve + delta, ROW-PANEL-per-XCD mapping (R13-proven:
// FETCH 350->81MB, g34 124us). XCD x owns output-row panel by in [8x,8x+8) x all
// bx. Retrieve: A = sigma(Q) in 4 K-segments; c_m folded into the accumulator
// between segments (acc *= ratT plane) -> no Ac materialization.
__global__ __launch_bounds__(256, 4) void g34_fused(
    const u16* __restrict__ sQ, const u16* __restrict__ MemT,
    const u16* __restrict__ sk, const float* __restrict__ V,
    const float* __restrict__ knorm, const float* __restrict__ ratT,
    float* __restrict__ out, u16* __restrict__ deltaT)
{
    __shared__ u16 As[2 * 4096];
    __shared__ u16 Bs[2 * 4096];
    int hw = blockIdx.x;
    int x   = hw & 7;            // XCD (HW round-robins blockIdx % 8)
    int l   = hw >> 3;           // [0,128) within XCD
    int z   = l >> 6;            // 0: retrieve (hw<512), 1: delta
    int idx = l & 63;
    int by  = x * 8 + (idx >> 3);  // XCD-owned row-panel range
    int bx  = idx & 7;
    int rb = by * 128, cb = bx * 128;
    int lane = threadIdx.x & 63, wid = threadIdx.x >> 6;
    int wr = wid >> 1;
    f32x4 acc[4][4];
    #pragma unroll
    for (int i = 0; i < 4; ++i)
        #pragma unroll
        for (int j = 0; j < 4; ++j) {
            f32x4 zz = {0.0f, 0.0f, 0.0f, 0.0f};
            acc[i][j] = zz;
        }
    if (z == 0) {
        #pragma unroll 1
        for (int m = 0; m < M_; ++m) {
            gemm_seg(As, Bs, sQ, D_, 0, MemT, M_ * D_, m * D_, rb, cb, D_, acc);
            const float* rp = ratT + (size_t)m * N_;
            #pragma unroll
            for (int mi = 0; mi < 4; ++mi) {
                int row0 = rb + wr * 64 + mi * 16 + (lane >> 4) * 4;
                float4 rt = *(const float4*)(rp + row0);
                #pragma unroll
                for (int ni = 0; ni < 4; ++ni) {
                    acc[mi][ni][0] *= rt.x; acc[mi][ni][1] *= rt.y;
                    acc[mi][ni][2] *= rt.z; acc[mi][ni][3] *= rt.w;
                }
            }
        }
        epi_out(acc, out, rb, cb);
    } else {
        gemm_seg(As, Bs, sk, D_, 0, MemT, M_ * D_, 0, rb, cb, D_, acc);
        epi_delta(acc, V, knorm, deltaT, rb, cb);
    }
}

// ---------------- update: out_mem(D,D) += (skT * deltaT^T)/N, split-K=8, fp32 atomics.
// K-SLICE-per-XCD mapping: kz = hw&7 == XCD -> each XCD reads only its
// skT/deltaT k-slice (2+2MB, L2-resident) instead of re-streaming 32MB.
#define KSPLIT 8
__global__ __launch_bounds__(256, 4) void g5_update(
    const u16* __restrict__ skT, const u16* __restrict__ deltaT,
    float* __restrict__ memout)
{
    __shared__ u16 As[2 * 4096];
    __shared__ u16 Bs[2 * 4096];
    f32x4 acc[4][4];
    #pragma unroll
    for (int i = 0; i < 4; ++i)
        #pragma unroll
        for (int j = 0; j < 4; ++j) {
            f32x4 zz = {0.0f, 0.0f, 0.0f, 0.0f};
            acc[i][j] = zz;
        }
    int hw = blockIdx.x;
    int kz = hw & 7;             // XCD owns one k-slice
    int l  = hw >> 3;            // [0,64)
    int by = l >> 3, bx = l & 7;
    int rb = by * 128, cb = bx * 128;
    int k0 = kz * (N_ / KSPLIT);
    gemm_seg(As, Bs, skT, N_, k0, deltaT, N_, k0, rb, cb, N_ / KSPLIT, acc);
    int lane = threadIdx.x & 63, wid = threadIdx.x >> 6;
    int wr = wid >> 1, wc = wid & 1, r15 = lane & 15;
    const float sc = 1.0f / (float)N_;
    #pragma unroll
    for (int mi = 0; mi < 4; ++mi) {
        int row0 = rb + wr * 64 + mi * 16 + (lane >> 4) * 4;
        #pragma unroll
        for (int ni = 0; ni < 4; ++ni) {
            int col = cb + wc * 64 + ni * 16 + r15;
            #pragma unroll
            for (int r = 0; r < 4; ++r)
                atomicAdd(memout + (size_t)(row0 + r) * D_ + col, acc[mi][ni][r] * sc);
        }
    }
}

extern "C" void kernel_launch(void* const* d_in, const int* in_sizes, int n_in,
                              void* d_out, int out_size, void* d_ws, size_t ws_size,
                              hipStream_t stream) {
    const float* Q     = (const float*)d_in[0];
    const float* K     = (const float*)d_in[1];
    const float* V     = (const float*)d_in[2];
    const float* Mem   = (const float*)d_in[3];
    const float* Mnorm = (const float*)d_in[4];

    float* out      = (float*)d_out;
    float* out_mem  = out + (size_t)N_ * D_;        // D*D
    float* out_norm = out_mem + (size_t)D_ * D_;    // D

    // ---- workspace layout (needs ~74MB; ws >= 121MB proven in prior rounds) ----
    // [0,1MB):   fp32 stats: qnorm(M*N) knorm(N) colsum(D) ratT(4*N)
    // [1,9MB):   MemT  bf16 [1024][4096]
    // [9,25MB):  sk    bf16 [8192][1024]
    // [25,41MB): skT   bf16 [1024][8192]
    // [41,57MB): sQ    bf16 [8192][1024]
    // [57,73MB): deltaT bf16 [1024][8192]
    char* wsb = (char*)d_ws;
    float* qnorm   = (float*)wsb;                   // 32768
    float* knorm   = qnorm + (size_t)M_ * N_;       // 8192
    float* colsum  = knorm + N_;                    // 1024
    float* ratT    = colsum + D_;                   // 4*N = 32768 (16B aligned)
    u16* MemT   = (u16*)(wsb + (size_t)1  * (1 << 20));
    u16* sk     = (u16*)(wsb + (size_t)9  * (1 << 20));
    u16* skT    = (u16*)(wsb + (size_t)25 * (1 << 20));
    u16* sQ     = (u16*)(wsb + (size_t)41 * (1 << 20));
    u16* deltaT = (u16*)(wsb + (size_t)57 * (1 << 20));

    hipLaunchKernelGGL(k1_stats, dim3(N_), dim3(256), 0, stream, Q, Mnorm, qnorm, sQ, knorm, colsum);
    hipLaunchKernelGGL(prep_km, dim3(3072), dim3(256), 0, stream,
                       K, Mnorm, Mem, sk, skT, colsum, knorm, MemT, out_mem);
    hipLaunchKernelGGL(k2_wc, dim3(32), dim3(256), 0, stream,
                       Mnorm, qnorm, colsum, ratT, out_norm);
    hipLaunchKernelGGL(g34_fused, dim3(1024), dim3(256), 0, stream,
                       sQ, MemT, sk, V, knorm, ratT, out, deltaT);
    hipLaunchKernelGGL(g5_update, dim3(512), dim3(256), 0, stream, skT, deltaT, out_mem);
}